// Round 1
// baseline (204.135 us; speedup 1.0000x reference)
//
#include <hip/hip_runtime.h>

// B=262144 batches, each: solve min ||A w - r||, A = [-x1,-x2,-x3, 1] (32x4), r = x0.
// Normal equations: w = (A^T A)^{-1} A^T r via 13 running sums + 4x4 Cholesky.
// pad_mask (d_in[1]) is unused by the reference -> never read (saves 8 MiB traffic).

__global__ __launch_bounds__(256) void basicls_kernel(const float* __restrict__ x,
                                                      float* __restrict__ out,
                                                      int B) {
    int b = blockIdx.x * blockDim.x + threadIdx.x;
    if (b >= B) return;

    const float4* __restrict__ xb = reinterpret_cast<const float4*>(x) + (size_t)b * 32;

    float s11 = 0.f, s12 = 0.f, s13 = 0.f, s22 = 0.f, s23 = 0.f, s33 = 0.f;
    float s1 = 0.f, s2 = 0.f, s3 = 0.f;
    float t1 = 0.f, t2 = 0.f, t3 = 0.f, t0 = 0.f;

#pragma unroll
    for (int m = 0; m < 32; ++m) {
        float4 v = xb[m];
        float r  = v.x;
        float a1 = v.y, a2 = v.z, a3 = v.w;
        s11 = fmaf(a1, a1, s11);
        s12 = fmaf(a1, a2, s12);
        s13 = fmaf(a1, a3, s13);
        s22 = fmaf(a2, a2, s22);
        s23 = fmaf(a2, a3, s23);
        s33 = fmaf(a3, a3, s33);
        s1 += a1; s2 += a2; s3 += a3;
        t1 = fmaf(a1, r, t1);
        t2 = fmaf(a2, r, t2);
        t3 = fmaf(a3, r, t3);
        t0 += r;
    }

    // Gram matrix G = A^T A and rhs = A^T r.
    float G[4][4];
    G[0][0] = s11; G[0][1] = s12; G[0][2] = s13; G[0][3] = -s1;
    G[1][0] = s12; G[1][1] = s22; G[1][2] = s23; G[1][3] = -s2;
    G[2][0] = s13; G[2][1] = s23; G[2][2] = s33; G[2][3] = -s3;
    G[3][0] = -s1; G[3][1] = -s2; G[3][2] = -s3; G[3][3] = 32.0f;
    float rhs[4] = { -t1, -t2, -t3, t0 };

    // Cholesky factorization G = L L^T (SPD since A full column rank).
    float L[4][4];
#pragma unroll
    for (int k = 0; k < 4; ++k) {
        float d = G[k][k];
#pragma unroll
        for (int j = 0; j < 4; ++j) {
            if (j < k) d = fmaf(-L[k][j], L[k][j], d);
        }
        float lkk = sqrtf(fmaxf(d, 1e-30f));
        L[k][k] = lkk;
        float inv = __frcp_rn(lkk);
#pragma unroll
        for (int i = 0; i < 4; ++i) {
            if (i > k) {
                float s = G[i][k];
#pragma unroll
                for (int j = 0; j < 4; ++j) {
                    if (j < k) s = fmaf(-L[i][j], L[k][j], s);
                }
                L[i][k] = s * inv;
            }
        }
    }

    // Forward solve L y = rhs.
    float y[4];
#pragma unroll
    for (int i = 0; i < 4; ++i) {
        float s = rhs[i];
#pragma unroll
        for (int j = 0; j < 4; ++j) {
            if (j < i) s = fmaf(-L[i][j], y[j], s);
        }
        y[i] = s * __frcp_rn(L[i][i]);
    }

    // Back solve L^T w = y.
    float w[4];
#pragma unroll
    for (int i = 3; i >= 0; --i) {
        float s = y[i];
#pragma unroll
        for (int j = 0; j < 4; ++j) {
            if (j > i) s = fmaf(-L[j][i], w[j], s);
        }
        w[i] = s * __frcp_rn(L[i][i]);
    }

    float4 wv = make_float4(w[0], w[1], w[2], w[3]);
    reinterpret_cast<float4*>(out)[b] = wv;
}

extern "C" void kernel_launch(void* const* d_in, const int* in_sizes, int n_in,
                              void* d_out, int out_size, void* d_ws, size_t ws_size,
                              hipStream_t stream) {
    const float* x = (const float*)d_in[0];
    // d_in[1] = pad_mask: unused by the reference computation.
    float* out = (float*)d_out;
    int B = in_sizes[0] / (32 * 4);
    dim3 block(256);
    dim3 grid((B + 255) / 256);
    basicls_kernel<<<grid, block, 0, stream>>>(x, out, B);
}

// Round 2
// 201.226 us; speedup vs baseline: 1.0145x; 1.0145x over previous
//
#include <hip/hip_runtime.h>

// B=262144 batches; per batch solve min ||A w - r||, A=[-x1,-x2,-x3,1] (32x4), r=x0.
// Normal equations via 13 running sums + 4x4 Cholesky.
// R2: coalesced global->LDS staging (global_load_lds x16B), rotated LDS reads
// to spread bank groups, one thread per batch. pad_mask unused by reference.

#define GLOBAL_AS __attribute__((address_space(1)))
#define LDS_AS    __attribute__((address_space(3)))

__device__ __forceinline__ void async_copy16(const float4* gptr, float4* lptr) {
    __builtin_amdgcn_global_load_lds((const GLOBAL_AS void*)gptr,
                                     (LDS_AS void*)lptr, 16, 0, 0);
}

__global__ __launch_bounds__(64) void basicls_kernel(const float* __restrict__ x,
                                                     float* __restrict__ out) {
    __shared__ float4 tile[64 * 32];   // 32 KiB: 64 batches x 32 rows (float4)

    const int t  = threadIdx.x;        // 0..63, one wave
    const int b0 = blockIdx.x * 64;    // first batch of this tile

    // Stage 64 batches (32 KiB) global->LDS. Each issue: 64 lanes x 16B = 1 KiB
    // contiguous; lane i writes lds_base + i*16 (wave-uniform base + lane*size).
    const float4* src = reinterpret_cast<const float4*>(x) + (size_t)b0 * 32;
#pragma unroll
    for (int k = 0; k < 32; ++k) {
        async_copy16(src + k * 64 + t, tile + k * 64);
    }
    __syncthreads();   // drains vmcnt(0) before s_barrier -> LDS writes visible

    // Thread t computes batch b0+t. Read its 32 rows in rotated order so the
    // 64 lanes spread over all 8 LDS bank groups each step.
    const int base = t * 32;
    float s11 = 0.f, s12 = 0.f, s13 = 0.f, s22 = 0.f, s23 = 0.f, s33 = 0.f;
    float s1 = 0.f, s2 = 0.f, s3 = 0.f;
    float t1 = 0.f, t2 = 0.f, t3 = 0.f, t0 = 0.f;

#pragma unroll
    for (int m = 0; m < 32; ++m) {
        int idx = base + ((m + t) & 31);
        float4 v = tile[idx];
        float r  = v.x;
        float a1 = v.y, a2 = v.z, a3 = v.w;
        s11 = fmaf(a1, a1, s11);
        s12 = fmaf(a1, a2, s12);
        s13 = fmaf(a1, a3, s13);
        s22 = fmaf(a2, a2, s22);
        s23 = fmaf(a2, a3, s23);
        s33 = fmaf(a3, a3, s33);
        s1 += a1; s2 += a2; s3 += a3;
        t1 = fmaf(a1, r, t1);
        t2 = fmaf(a2, r, t2);
        t3 = fmaf(a3, r, t3);
        t0 += r;
    }

    // Gram matrix G = A^T A, rhs = A^T r.
    float G[4][4];
    G[0][0] = s11; G[0][1] = s12; G[0][2] = s13; G[0][3] = -s1;
    G[1][0] = s12; G[1][1] = s22; G[1][2] = s23; G[1][3] = -s2;
    G[2][0] = s13; G[2][1] = s23; G[2][2] = s33; G[2][3] = -s3;
    G[3][0] = -s1; G[3][1] = -s2; G[3][2] = -s3; G[3][3] = 32.0f;
    float rhs[4] = { -t1, -t2, -t3, t0 };

    // Cholesky G = L L^T.
    float L[4][4];
#pragma unroll
    for (int k = 0; k < 4; ++k) {
        float d = G[k][k];
#pragma unroll
        for (int j = 0; j < 4; ++j) {
            if (j < k) d = fmaf(-L[k][j], L[k][j], d);
        }
        float lkk = sqrtf(fmaxf(d, 1e-30f));
        L[k][k] = lkk;
        float inv = __frcp_rn(lkk);
#pragma unroll
        for (int i = 0; i < 4; ++i) {
            if (i > k) {
                float s = G[i][k];
#pragma unroll
                for (int j = 0; j < 4; ++j) {
                    if (j < k) s = fmaf(-L[i][j], L[k][j], s);
                }
                L[i][k] = s * inv;
            }
        }
    }

    // Forward solve L y = rhs.
    float y[4];
#pragma unroll
    for (int i = 0; i < 4; ++i) {
        float s = rhs[i];
#pragma unroll
        for (int j = 0; j < 4; ++j) {
            if (j < i) s = fmaf(-L[i][j], y[j], s);
        }
        y[i] = s * __frcp_rn(L[i][i]);
    }

    // Back solve L^T w = y.
    float w[4];
#pragma unroll
    for (int i = 3; i >= 0; --i) {
        float s = y[i];
#pragma unroll
        for (int j = 0; j < 4; ++j) {
            if (j > i) s = fmaf(-L[j][i], w[j], s);
        }
        w[i] = s * __frcp_rn(L[i][i]);
    }

    reinterpret_cast<float4*>(out)[b0 + t] = make_float4(w[0], w[1], w[2], w[3]);
}

extern "C" void kernel_launch(void* const* d_in, const int* in_sizes, int n_in,
                              void* d_out, int out_size, void* d_ws, size_t ws_size,
                              hipStream_t stream) {
    const float* x = (const float*)d_in[0];
    // d_in[1] = pad_mask: unused by the reference computation.
    float* out = (float*)d_out;
    int B = in_sizes[0] / (32 * 4);        // 262144
    dim3 block(64);
    dim3 grid(B / 64);                     // 4096 one-wave tiles
    basicls_kernel<<<grid, block, 0, stream>>>(x, out);
}

// Round 3
// 198.992 us; speedup vs baseline: 1.0258x; 1.0112x over previous
//
#include <hip/hip_runtime.h>

// B=262144 batches; per batch solve min ||A w - r||, A=[-x1,-x2,-x3,1] (32x4), r=x0.
// Normal equations via 13 running sums + 4x4 Cholesky.
// R3: 4-wave blocks, 8 KiB staging per wave (16 batches), 20 waves/CU.
// 4 lanes per batch (8 rows each, rotated for conflict-free b128), DPP quad
// shfl_xor combine, redundant solve, lane0-of-quad stores.

#define GLOBAL_AS __attribute__((address_space(1)))
#define LDS_AS    __attribute__((address_space(3)))

__device__ __forceinline__ void async_copy16(const float4* gptr, float4* lptr) {
    __builtin_amdgcn_global_load_lds((const GLOBAL_AS void*)gptr,
                                     (LDS_AS void*)lptr, 16, 0, 0);
}

__global__ __launch_bounds__(256) void basicls_kernel(const float* __restrict__ x,
                                                      float* __restrict__ out) {
    // 4 waves x 512 float4 (8 KiB) = 32 KiB per block.
    __shared__ float4 tile[4 * 512];

    const int tid = threadIdx.x;
    const int w   = tid >> 6;          // wave 0..3
    const int t   = tid & 63;          // lane 0..63
    const int b0  = blockIdx.x * 64;   // 64 batches per block (16 per wave)

    // Wave w stages batches [b0 + w*16, b0 + w*16 + 16): 512 float4 = 8 KiB,
    // in 8 issues of 64 lanes x 16 B (wave-uniform LDS base + lane*16).
    const float4* src = reinterpret_cast<const float4*>(x) + (size_t)(b0 + w * 16) * 32;
    float4* chunk = tile + w * 512;
#pragma unroll
    for (int k = 0; k < 8; ++k) {
        async_copy16(src + k * 64 + t, chunk + k * 64);
    }
    __syncthreads();   // vmcnt(0) drain + barrier -> LDS visible

    // Lane roles: quad g = t>>2 owns batch (b0 + w*16 + g); sub = t&3 covers
    // rows m = sub*8 + j. Row order rotated by g so the wave's 64 b128 reads
    // spread across all 8 LDS bank groups each step.
    const int g   = t >> 2;
    const int sub = t & 3;

    float s11 = 0.f, s12 = 0.f, s13 = 0.f, s22 = 0.f, s23 = 0.f, s33 = 0.f;
    float s1 = 0.f, s2 = 0.f, s3 = 0.f;
    float t1 = 0.f, t2 = 0.f, t3 = 0.f, t0 = 0.f;

#pragma unroll
    for (int j = 0; j < 8; ++j) {
        int jj = (j + g) & 7;
        float4 v = chunk[g * 32 + sub * 8 + jj];
        float r  = v.x;
        float a1 = v.y, a2 = v.z, a3 = v.w;
        s11 = fmaf(a1, a1, s11);
        s12 = fmaf(a1, a2, s12);
        s13 = fmaf(a1, a3, s13);
        s22 = fmaf(a2, a2, s22);
        s23 = fmaf(a2, a3, s23);
        s33 = fmaf(a3, a3, s33);
        s1 += a1; s2 += a2; s3 += a3;
        t1 = fmaf(a1, r, t1);
        t2 = fmaf(a2, r, t2);
        t3 = fmaf(a3, r, t3);
        t0 += r;
    }

    // Combine the 4 partial sums within each quad (xor 1, xor 2 -> DPP).
#define QUAD_REDUCE(v) \
    v += __shfl_xor(v, 1); \
    v += __shfl_xor(v, 2);
    QUAD_REDUCE(s11) QUAD_REDUCE(s12) QUAD_REDUCE(s13)
    QUAD_REDUCE(s22) QUAD_REDUCE(s23) QUAD_REDUCE(s33)
    QUAD_REDUCE(s1)  QUAD_REDUCE(s2)  QUAD_REDUCE(s3)
    QUAD_REDUCE(t1)  QUAD_REDUCE(t2)  QUAD_REDUCE(t3)
    QUAD_REDUCE(t0)
#undef QUAD_REDUCE

    // Gram matrix G = A^T A, rhs = A^T r. All 4 lanes of the quad solve
    // redundantly (no divergence); lane sub==0 stores.
    float G[4][4];
    G[0][0] = s11; G[0][1] = s12; G[0][2] = s13; G[0][3] = -s1;
    G[1][0] = s12; G[1][1] = s22; G[1][2] = s23; G[1][3] = -s2;
    G[2][0] = s13; G[2][1] = s23; G[2][2] = s33; G[2][3] = -s3;
    G[3][0] = -s1; G[3][1] = -s2; G[3][2] = -s3; G[3][3] = 32.0f;
    float rhs[4] = { -t1, -t2, -t3, t0 };

    float L[4][4];
#pragma unroll
    for (int k = 0; k < 4; ++k) {
        float d = G[k][k];
#pragma unroll
        for (int j = 0; j < 4; ++j) {
            if (j < k) d = fmaf(-L[k][j], L[k][j], d);
        }
        float lkk = sqrtf(fmaxf(d, 1e-30f));
        L[k][k] = lkk;
        float inv = __frcp_rn(lkk);
#pragma unroll
        for (int i = 0; i < 4; ++i) {
            if (i > k) {
                float s = G[i][k];
#pragma unroll
                for (int j = 0; j < 4; ++j) {
                    if (j < k) s = fmaf(-L[i][j], L[k][j], s);
                }
                L[i][k] = s * inv;
            }
        }
    }

    float y[4];
#pragma unroll
    for (int i = 0; i < 4; ++i) {
        float s = rhs[i];
#pragma unroll
        for (int j = 0; j < 4; ++j) {
            if (j < i) s = fmaf(-L[i][j], y[j], s);
        }
        y[i] = s * __frcp_rn(L[i][i]);
    }

    float wv[4];
#pragma unroll
    for (int i = 3; i >= 0; --i) {
        float s = y[i];
#pragma unroll
        for (int j = 0; j < 4; ++j) {
            if (j > i) s = fmaf(-L[j][i], wv[j], s);
        }
        wv[i] = s * __frcp_rn(L[i][i]);
    }

    if (sub == 0) {
        int b = b0 + w * 16 + g;
        reinterpret_cast<float4*>(out)[b] = make_float4(wv[0], wv[1], wv[2], wv[3]);
    }
}

extern "C" void kernel_launch(void* const* d_in, const int* in_sizes, int n_in,
                              void* d_out, int out_size, void* d_ws, size_t ws_size,
                              hipStream_t stream) {
    const float* x = (const float*)d_in[0];
    // d_in[1] = pad_mask: unused by the reference computation.
    float* out = (float*)d_out;
    int B = in_sizes[0] / (32 * 4);        // 262144
    dim3 block(256);
    dim3 grid(B / 64);                     // 4096 blocks, 64 batches each
    basicls_kernel<<<grid, block, 0, stream>>>(x, out);
}